// Round 2
// baseline (9347.031 us; speedup 1.0000x reference)
//
#include <hip/hip_runtime.h>
#include <stdint.h>

// ---------------------------------------------------------------------------
// 3-layer packed-sequence LSTM, B=64 T=2048 D=40 H=164, FC->7. fp32 in/out.
//
// v3: MFMA-batched recurrence + gemm/rec fusion.
//
//  * krec is now a per-(layer, 16-batch-group) block (12 blocks total) that
//    computes the recurrent projection as [16x164]@[164x656] MFMA GEMM per
//    timestep. Gate rows are padded 164->176 so the 4 gate tiles of one
//    element block are 16-aligned: wave w (of 11) owns elements 16w..16w+15
//    and tiles {i,f,g,o} at rows g*176+16w.. -> each lane ends up holding
//    all 4 gates of ONE element for 4 batches in its accumulators. Cell
//    update is fully in-lane (no shuffles, no gates LDS), per-batch length
//    masks freeze c (regs) and h (regs, republished each step).
//    h double-buffered in LDS, ONE barrier per step.
//    W_hh resident in regs: 96 dwords/lane x 704 lanes = exactly W_hh.
//  * kgemm and krec fused into one kernel kstep_f with a 2-slot-per-layer
//    staircase: launch j = gemm(l, j-2l) || rec(l, j-2l-1). All producer->
//    consumer edges cross a launch boundary; gx is double-buffered by chunk
//    parity to remove the gemm(l,ch+1) || rec(l,ch) WAR hazard.
//    204 blocks < 256 CUs -> gemm fully overlaps rec.
//  * Sequential fallback (1 gx slot, old skew) if ws_size is too small.
// ---------------------------------------------------------------------------

#define TT 2048
#define BB 64
#define GG 656   // 4*H (compact gate rows)
#define HH 164
#define EP 176   // padded elems per gate (16-aligned)
#define GP 704   // 4*EP padded gate rows
#define KPH 192  // K padded to 192 halves
#define KPD 96   // = KPH/2 dwords
#define CC 128   // chunk timesteps
#define NCH (TT/CC)   // 16

typedef _Float16 half2v __attribute__((ext_vector_type(2)));
typedef _Float16 half8  __attribute__((ext_vector_type(8)));
typedef float    f32x4  __attribute__((ext_vector_type(4)));

// ---- workspace layout (bytes) ----
#define SZ_WIH   ((size_t)3*GG*KPH*2)          // 755,712   f16 [3][656][192]
#define SZ_WHH   ((size_t)3*GP*KPH*2)          // 811,008   f16 [3][704][192]
#define SZ_GX1   ((size_t)3*4*CC*GG*16*2)      // 32,243,712 f16 [3][4][128][656][16]
#define GX_SLOT_HALVES ((size_t)3*4*CC*GG*16)  // halves per gx slot
#define SZ_HR    ((size_t)2*2*BB*CC*96*4)      // 12,582,912 dw [2l][2slot][64][128][96]
#define SZ_SC    ((size_t)3*BB*HH*4)           // f32 c-state
#define SZ_SH    ((size_t)3*BB*96*4)           // dword h-state (f16 pairs)

__device__ __forceinline__ float sigmf(float x) { return 1.0f/(1.0f + __expf(-x)); }
__device__ __forceinline__ float tanhf_(float x) { return 2.0f/(1.0f + __expf(-2.0f*x)) - 1.0f; }

// ---------------------------------------------------------------------------
// weight prep: wih compact [3][656][192] (K zero-padded), whh padded
// [3][704][192] (rows g*176+e, zero for e>=164; K zero-padded)
// ---------------------------------------------------------------------------
__global__ void kprep_w(const float* wih0, const float* whh0,
                        const float* wih1, const float* whh1,
                        const float* wih2, const float* whh2,
                        _Float16* wih16, _Float16* whh16) {
  int i = threadIdx.x + blockIdx.x * blockDim.x;
  if (i >= 3*GP*KPH) return;
  int l = i / (GP*KPH);
  int r2 = i - l*(GP*KPH);
  int prow = r2 / KPH;
  int k = r2 - prow*KPH;
  const float* wihl = (l == 0) ? wih0 : ((l == 1) ? wih1 : wih2);
  const float* whhl = (l == 0) ? whh0 : ((l == 1) ? whh1 : whh2);
  // whh padded row
  int g = prow / EP, e = prow - g*EP;
  float vh = 0.f;
  if (e < HH && k < HH) vh = whhl[(size_t)(g*HH + e)*HH + k];
  whh16[((size_t)l*GP + prow)*KPH + k] = (_Float16)vh;
  // wih compact row
  if (prow < GG) {
    float vi = 0.f;
    if (l == 0) { if (k < 40) vi = wihl[(size_t)prow*40 + k]; }
    else        { if (k < HH) vi = wihl[(size_t)prow*HH + k]; }
    wih16[((size_t)l*GG + prow)*KPH + k] = (_Float16)vi;
  }
}

// ---------------------------------------------------------------------------
// input-projection GEMM body for one (l, b, chunk): gx[t][656][16bq] f16
// 704 threads enter; all stage + barrier, tid<256 (4 waves) do MFMA.
// ---------------------------------------------------------------------------
__device__ __forceinline__ void gemm_body(
    int l, int b, int ch, const int* lengths, const float* x,
    const uint32_t* wihw, const uint32_t* hring, uint16_t* gxs,
    uint32_t* smem, int tid) {
  int len = lengths[b]; if (len < 1) len = 1; if (len > TT) len = TT;
  if (ch*CC >= len) return;                    // whole chunk past this sequence
  const int active = (tid < 256);
  const int lane = tid & 63, wv = tid >> 6;
  const int quad = lane >> 4, n15 = lane & 15;
  const int Kt = (l == 0) ? 2 : 6;
  uint16_t* gxo = gxs + ((size_t)(l*4 + (b >> 4))*CC)*GG*16;
  const int bq = b & 15;
  const uint32_t* hbs = (l > 0)
      ? hring + ((size_t)((l-1)*2 + (ch & 1))*BB + b)*CC*96 : (const uint32_t*)0;

  for (int st = 0; st < 4; ++st) {
    // ---- stage A-tile (32 timesteps x K halves), all 704 threads ----
    if (l == 0) {
      for (int idx = tid; idx < 32*32; idx += 704) {
        int row = idx >> 5, dw = idx & 31;
        int t = ch*CC + st*32 + row;
        uint32_t v = 0;
        if (dw < 20) {
          const float* xs = x + ((size_t)b*TT + t)*40 + dw*2;
          half2v pp; pp[0] = (_Float16)xs[0]; pp[1] = (_Float16)xs[1];
          v = __builtin_bit_cast(uint32_t, pp);
        }
        smem[row*100 + dw] = v;
      }
    } else {
      for (int idx = tid; idx < 32*96; idx += 704) {
        int row = idx / 96, dw = idx - row*96;
        smem[row*100 + dw] = hbs[(size_t)(st*32 + row)*96 + dw];
      }
    }
    __syncthreads();

    if (active) {
      const half8* asrc = (const half8*)smem;   // row stride 25 half8
      for (int nt = wv; nt < 41; nt += 4) {
        int wrow = nt*16 + n15;
        const half8* bsrc = (const half8*)(wihw + ((size_t)l*GG + wrow)*KPD);
        f32x4 a0 = {0.f,0.f,0.f,0.f};
        f32x4 a1 = {0.f,0.f,0.f,0.f};
        for (int kk = 0; kk < Kt; ++kk) {
          half8 bf  = bsrc[kk*4 + quad];
          half8 af0 = asrc[ n15      *25 + kk*4 + quad];
          half8 af1 = asrc[(n15 + 16)*25 + kk*4 + quad];
          a0 = __builtin_amdgcn_mfma_f32_16x16x32_f16(af0, bf, a0, 0, 0, 0);
          a1 = __builtin_amdgcn_mfma_f32_16x16x32_f16(af1, bf, a1, 0, 0, 0);
        }
        #pragma unroll
        for (int r = 0; r < 4; ++r) {
          int trow = st*32 + quad*4 + r;        // C/D: col=lane&15, row=quad*4+reg
          _Float16 h0 = (_Float16)a0[r];
          _Float16 h1 = (_Float16)a1[r];
          gxo[((size_t)trow*GG + wrow)*16 + bq]        = __builtin_bit_cast(uint16_t, h0);
          gxo[((size_t)(trow + 16)*GG + wrow)*16 + bq] = __builtin_bit_cast(uint16_t, h1);
        }
      }
    }
    __syncthreads();
  }
}

// ---------------------------------------------------------------------------
// MFMA recurrence body for one (l, batch-group of 16, chunk). 704 thr.
// wave wv owns elements e = 16wv..16wv+15; lane (n15,quad) holds all 4 gates
// of element e = 16wv+n15 for batches quad*4+r in acc[g][r].
// ---------------------------------------------------------------------------
__device__ __forceinline__ void rec_body(
    int l, int bg, int ch, const int* lengths,
    const float* b0, const float* b1, const float* b2,
    const uint32_t* whhw, const uint16_t* gxs, uint32_t* hring,
    float* state_c, uint32_t* state_h, uint32_t* smem, int tid) {

  int maxlen = 1;
  #pragma unroll
  for (int bi = 0; bi < 16; ++bi) {
    int L = lengths[bg*16 + bi]; if (L < 1) L = 1; if (L > TT) L = TT;
    if (L > maxlen) maxlen = L;
  }
  const int t0 = ch*CC;
  if (t0 >= maxlen) return;                     // group fully frozen
  int t1 = t0 + CC; if (t1 > maxlen) t1 = maxlen;

  const int wv = tid >> 6, ln = tid & 63;
  const int quad = ln >> 4, n15 = ln & 15;
  const int e = wv*16 + n15;                    // 0..175
  const int evalid = (e < HH);

  int lenv[4];
  #pragma unroll
  for (int r = 0; r < 4; ++r) {
    int L = lengths[bg*16 + quad*4 + r]; if (L < 1) L = 1; if (L > TT) L = TT;
    lenv[r] = L;
  }

  // resident W_hh fragments: 4 gates x 6 k-steps, half8 each (96 dwords)
  half8 wB[24];
  {
    const half8* wb8 = (const half8*)(whhw + (size_t)l*GP*KPD);
    #pragma unroll
    for (int g = 0; g < 4; ++g) {
      int row = g*EP + e;
      #pragma unroll
      for (int kk = 0; kk < 6; ++kk)
        wB[g*6 + kk] = wb8[(size_t)row*24 + kk*4 + quad];
    }
  }
  const float* bp = (l == 0) ? b0 : ((l == 1) ? b1 : b2);
  float bias[4];
  #pragma unroll
  for (int g = 0; g < 4; ++g) bias[g] = evalid ? bp[g*HH + e] : 0.f;

  float creg[4] = {0.f, 0.f, 0.f, 0.f};
  if (ch > 0 && evalid) {
    #pragma unroll
    for (int r = 0; r < 4; ++r)
      creg[r] = state_c[((size_t)l*BB + bg*16 + quad*4 + r)*HH + e];
  }

  // h double buffer in LDS: [16 batches][100 dwords], halves 164..191 = 0
  uint32_t* hb0 = smem;
  uint32_t* hb1 = smem + 1600;
  for (int i2 = tid; i2 < 1600; i2 += 704) {
    int bb = i2 / 100, dd = i2 - bb*100;
    uint32_t v = 0;
    if (dd < 96 && ch > 0) v = state_h[((size_t)l*BB + bg*16 + bb)*96 + dd];
    hb0[i2] = v; hb1[i2] = v;
  }
  __syncthreads();

  // per-lane h bits for its 4 (batch, e) slots (re-published every step so
  // frozen sequences keep valid h in BOTH buffers)
  uint16_t hbits[4];
  #pragma unroll
  for (int r = 0; r < 4; ++r)
    hbits[r] = ((const uint16_t*)hb0)[(quad*4 + r)*200 + e];

  uint32_t* hrb = (l < 2)
      ? hring + ((size_t)(l*2 + (ch & 1))*BB)*CC*96 : (uint32_t*)0;
  const uint16_t* gxb = gxs + ((size_t)(l*4 + bg)*CC)*GG*16;
  uint32_t* shb = state_h + ((size_t)l*BB + bg*16)*96;

  uint2 gxp[4] = {};
  if (evalid) {
    #pragma unroll
    for (int g = 0; g < 4; ++g)
      gxp[g] = *(const uint2*)(gxb + ((size_t)g*HH + e)*16 + quad*4);
  }

  int p = 0;
  for (int t = t0; t < t1; ++t) {
    uint32_t* hin  = p ? hb1 : hb0;
    uint32_t* hout = p ? hb0 : hb1;

    // acc init = bias + gx (this step's input projection)
    f32x4 acc[4];
    #pragma unroll
    for (int g = 0; g < 4; ++g) {
      const _Float16* gh = (const _Float16*)&gxp[g];
      #pragma unroll
      for (int r = 0; r < 4; ++r) acc[g][r] = bias[g] + (float)gh[r];
    }
    // prefetch next step's gx (hidden under MFMA + update)
    if (t + 1 < t1 && evalid) {
      int trow = t + 1 - t0;
      #pragma unroll
      for (int g = 0; g < 4; ++g)
        gxp[g] = *(const uint2*)(gxb + ((size_t)trow*GG + g*HH + e)*16 + quad*4);
    }
    // recurrent projection: [16x164] @ W_hh^T, 24 MFMA
    #pragma unroll
    for (int kk = 0; kk < 6; ++kk) {
      half8 af = *(const half8*)&hin[n15*100 + kk*16 + quad*4];
      acc[0] = __builtin_amdgcn_mfma_f32_16x16x32_f16(af, wB[kk],      acc[0], 0, 0, 0);
      acc[1] = __builtin_amdgcn_mfma_f32_16x16x32_f16(af, wB[6 + kk],  acc[1], 0, 0, 0);
      acc[2] = __builtin_amdgcn_mfma_f32_16x16x32_f16(af, wB[12 + kk], acc[2], 0, 0, 0);
      acc[3] = __builtin_amdgcn_mfma_f32_16x16x32_f16(af, wB[18 + kk], acc[3], 0, 0, 0);
    }
    // ring publish h(t-1) from hin
    if (hrb && t > t0) {
      int row = t - 1 - t0;
      for (int i2 = tid; i2 < 1536; i2 += 704) {
        int bb = i2 / 96, dd = i2 - bb*96;
        hrb[((size_t)(bg*16 + bb)*CC + row)*96 + dd] = hin[bb*100 + dd];
      }
    }
    // cell update: lane has gates i,f,g,o of element e for 4 batches
    #pragma unroll
    for (int r = 0; r < 4; ++r) {
      float gi = acc[0][r], gf = acc[1][r], gg2 = acc[2][r], go = acc[3][r];
      float cn = sigmf(gf)*creg[r] + sigmf(gi)*tanhf_(gg2);
      float hv = sigmf(go)*tanhf_(cn);
      if (t < lenv[r]) {                        // per-batch freeze
        creg[r] = cn;
        _Float16 h16 = (_Float16)hv;
        hbits[r] = __builtin_bit_cast(uint16_t, h16);
      }
      if (evalid)
        ((uint16_t*)hout)[(quad*4 + r)*200 + e] = hbits[r];
    }
    __syncthreads();                            // hout visible
    p ^= 1;
  }

  // final ring publish + persist state
  uint32_t* hfin = p ? hb1 : hb0;
  {
    int rowl = t1 - 1 - t0;
    for (int i2 = tid; i2 < 1536; i2 += 704) {
      int bb = i2 / 96, dd = i2 - bb*96;
      uint32_t v = hfin[bb*100 + dd];
      if (hrb) hrb[((size_t)(bg*16 + bb)*CC + rowl)*96 + dd] = v;
      shb[(size_t)bb*96 + dd] = v;
    }
  }
  if (evalid) {
    #pragma unroll
    for (int r = 0; r < 4; ++r)
      state_c[((size_t)l*BB + bg*16 + quad*4 + r)*HH + e] = creg[r];
  }
}

// ---------------------------------------------------------------------------
// fused step: blocks 0..191 = gemm(l, j-2l), blocks 192..203 = rec(l, j-2l-1)
// gx double-buffered by chunk parity (kills gemm(l,ch+1) || rec(l,ch) WAR).
// ---------------------------------------------------------------------------
__global__ __launch_bounds__(704) void kstep_f(
    int j, const int* lengths, const float* x,
    const uint32_t* wihw, const uint32_t* whhw,
    const float* b0, const float* b1, const float* b2,
    uint16_t* gx, uint32_t* hring, float* state_c, uint32_t* state_h) {
  __shared__ __align__(16) uint32_t smem[3200];
  const int blk = blockIdx.x, tid = threadIdx.x;
  if (blk < 192) {
    const int l = blk >> 6, b = blk & 63;
    const int ch = j - 2*l;
    if (ch < 0 || ch >= NCH) return;
    uint16_t* gxs = gx + (size_t)(ch & 1)*GX_SLOT_HALVES;
    gemm_body(l, b, ch, lengths, x, wihw, hring, gxs, smem, tid);
  } else {
    const int idx = blk - 192;
    if (idx >= 12) return;
    const int l = idx >> 2, bg = idx & 3;
    const int ch = j - 2*l - 1;
    if (ch < 0 || ch >= NCH) return;
    const uint16_t* gxs = gx + (size_t)(ch & 1)*GX_SLOT_HALVES;
    rec_body(l, bg, ch, lengths, b0, b1, b2, whhw, gxs, hring,
             state_c, state_h, smem, tid);
  }
}

// ---- sequential fallback (1 gx slot, old skew) ----
__global__ __launch_bounds__(704) void kgemm_s(
    int step, const int* lengths, const float* x,
    const uint32_t* wihw, uint16_t* gx, const uint32_t* hring) {
  __shared__ __align__(16) uint32_t smem[3200];
  const int l = blockIdx.x >> 6, b = blockIdx.x & 63;
  const int ch = step - l;
  if (ch < 0 || ch >= NCH) return;
  gemm_body(l, b, ch, lengths, x, wihw, hring, gx, smem, threadIdx.x);
}

__global__ __launch_bounds__(704) void krec_s(
    int step, const int* lengths,
    const float* b0, const float* b1, const float* b2,
    const uint32_t* whhw, const uint16_t* gx, uint32_t* hring,
    float* state_c, uint32_t* state_h) {
  __shared__ __align__(16) uint32_t smem[3200];
  const int idx = blockIdx.x;
  const int l = idx >> 2, bg = idx & 3;
  const int ch = step - l;
  if (ch < 0 || ch >= NCH) return;
  rec_body(l, bg, ch, lengths, b0, b1, b2, whhw, gx, hring,
           state_c, state_h, smem, threadIdx.x);
}

// ---------------------------------------------------------------------------
// FC epilogue on layer-2 final hidden state
// ---------------------------------------------------------------------------
__global__ void kfc(const float* fcw, const float* fcb,
                    const uint32_t* state_h, float* out) {
  int b = blockIdx.x, o = threadIdx.x;
  if (o >= 7) return;
  const uint16_t* h16 = (const uint16_t*)(state_h + (size_t)(2*BB + b)*96);
  float s = fcb[o];
  for (int m = 0; m < HH; ++m) {
    _Float16 hv = __builtin_bit_cast(_Float16, h16[m]);
    s += fcw[o*HH + m] * (float)hv;
  }
  out[b*7 + o] = s;
}

// ---------------------------------------------------------------------------
extern "C" void kernel_launch(void* const* d_in, const int* in_sizes, int n_in,
                              void* d_out, int out_size, void* d_ws, size_t ws_size,
                              hipStream_t stream) {
  const float* x      = (const float*)d_in[0];
  const int*  lengths = (const int*)  d_in[1];
  const float* wih0   = (const float*)d_in[2];
  const float* whh0   = (const float*)d_in[3];
  const float* b0     = (const float*)d_in[4];
  const float* wih1   = (const float*)d_in[5];
  const float* whh1   = (const float*)d_in[6];
  const float* b1     = (const float*)d_in[7];
  const float* wih2   = (const float*)d_in[8];
  const float* whh2   = (const float*)d_in[9];
  const float* b2     = (const float*)d_in[10];
  const float* fcw    = (const float*)d_in[11];
  const float* fcb    = (const float*)d_in[12];

  const size_t off_wih = 0;
  const size_t off_whh = SZ_WIH;
  const size_t off_gx  = SZ_WIH + SZ_WHH;
  const size_t tail    = SZ_HR + SZ_SC + SZ_SH;
  const size_t need_fused = off_gx + 2*SZ_GX1 + tail;   // ~78.8 MB
  const size_t need_seq   = off_gx + 1*SZ_GX1 + tail;   // ~46.6 MB
  const int fused = (ws_size >= need_fused);
  if (!fused && ws_size < need_seq) return;             // loud, clean failure
  const size_t gx_bytes = fused ? 2*SZ_GX1 : SZ_GX1;
  const size_t off_hr = off_gx + gx_bytes;
  const size_t off_sc = off_hr + SZ_HR;
  const size_t off_sh = off_sc + SZ_SC;

  char* ws = (char*)d_ws;
  _Float16* wih16 = (_Float16*)(ws + off_wih);
  _Float16* whh16 = (_Float16*)(ws + off_whh);
  uint16_t* gxw   = (uint16_t*)(ws + off_gx);
  uint32_t* hrw   = (uint32_t*)(ws + off_hr);
  float*    scw   = (float*)   (ws + off_sc);
  uint32_t* shw   = (uint32_t*)(ws + off_sh);

  hipLaunchKernelGGL(kprep_w, dim3((3*GP*KPH + 255)/256), dim3(256), 0, stream,
                     wih0, whh0, wih1, whh1, wih2, whh2, wih16, whh16);

  if (fused) {
    for (int jj = 0; jj <= NCH + 4; ++jj) {             // j = 0..20
      hipLaunchKernelGGL(kstep_f, dim3(204), dim3(704), 0, stream,
                         jj, lengths, x, (const uint32_t*)wih16,
                         (const uint32_t*)whh16, b0, b1, b2,
                         gxw, hrw, scw, shw);
    }
  } else {
    for (int i = 0; i < NCH + 2; ++i) {
      hipLaunchKernelGGL(kgemm_s, dim3(192), dim3(704), 0, stream,
                         i, lengths, x, (const uint32_t*)wih16, gxw,
                         (const uint32_t*)hrw);
      hipLaunchKernelGGL(krec_s, dim3(12), dim3(704), 0, stream,
                         i, lengths, b0, b1, b2, (const uint32_t*)whh16,
                         (const uint16_t*)gxw, hrw, scw, shw);
    }
  }

  hipLaunchKernelGGL(kfc, dim3(64), dim3(64), 0, stream,
                     fcw, fcb, shw, (float*)d_out);
}

// Round 3
// 9310.539 us; speedup vs baseline: 1.0039x; 1.0039x over previous
//
#include <hip/hip_runtime.h>
#include <stdint.h>

// ---------------------------------------------------------------------------
// 3-layer packed-sequence LSTM, B=64 T=2048 D=40 H=164, FC->7. fp32 in/out.
//
// v4: batch-major input GEMM (fixes v3's 232 MB/dispatch write amplification).
//
//  * gx layout [l][bg][t][656 rows][16 batches] (per parity slot). Written by
//    a gemm whose MFMA M-dim is the 16-batch group: block = (l, bg, 8-t
//    slice); per t, A=[16b x K] staged in LDS, B=W_ih rows; lane (n15,quad)
//    emits row nt*16+n15, batches quad*4..+3 as ONE 8-byte store -> a wave
//    covers 512 contiguous bytes. Reader (rec) unchanged, also coalesced.
//  * rec: per-(l, 16-batch-group) block, recurrent projection as
//    [16x164]@[164x656] MFMA per step; all 4 gates of an element land in one
//    lane; cell update fully in-lane; h double-buffered in LDS, ONE barrier
//    per step; per-batch length masks freeze c/h.
//  * fused staircase: launch j = gemm(l, j-2l) || rec(l, j-2l-1); gx parity
//    double-buffer kills the gemm(ch+1) || rec(ch) WAR hazard. 204 blocks.
//  * Sequential fallback (1 gx slot) if ws_size is too small.
// ---------------------------------------------------------------------------

#define TT 2048
#define BB 64
#define GG 656   // 4*H (compact gate rows)
#define HH 164
#define EP 176   // padded elems per gate (16-aligned)
#define GP 704   // 4*EP padded gate rows
#define KPH 192  // K padded to 192 halves
#define KPD 96   // = KPH/2 dwords
#define CC 128   // chunk timesteps
#define NCH (TT/CC)   // 16
#define TSL 8    // timesteps per gemm slice block
#define NSL (CC/TSL)  // 16 slices

typedef _Float16 half2v __attribute__((ext_vector_type(2)));
typedef _Float16 half8  __attribute__((ext_vector_type(8)));
typedef float    f32x4  __attribute__((ext_vector_type(4)));

// ---- workspace layout (bytes) ----
#define SZ_WIH   ((size_t)3*GG*KPH*2)          // f16 [3][656][192]
#define SZ_WHH   ((size_t)3*GP*KPH*2)          // f16 [3][704][192]
#define SZ_GX1   ((size_t)3*4*CC*GG*16*2)      // f16 [3][4][128][656][16] ~32.2MB
#define GX_SLOT_HALVES ((size_t)3*4*CC*GG*16)
#define SZ_HR    ((size_t)2*2*BB*CC*96*4)      // dw [2l][2slot][64][128][96]
#define SZ_SC    ((size_t)3*BB*HH*4)           // f32 c-state
#define SZ_SH    ((size_t)3*BB*96*4)           // dword h-state (f16 pairs)

__device__ __forceinline__ float sigmf(float x) { return 1.0f/(1.0f + __expf(-x)); }
__device__ __forceinline__ float tanhf_(float x) { return 2.0f/(1.0f + __expf(-2.0f*x)) - 1.0f; }

// ---------------------------------------------------------------------------
// weight prep: wih compact [3][656][192] (K zero-padded), whh padded
// [3][704][192] (rows g*176+e, zero for e>=164; K zero-padded)
// ---------------------------------------------------------------------------
__global__ void kprep_w(const float* wih0, const float* whh0,
                        const float* wih1, const float* whh1,
                        const float* wih2, const float* whh2,
                        _Float16* wih16, _Float16* whh16) {
  int i = threadIdx.x + blockIdx.x * blockDim.x;
  if (i >= 3*GP*KPH) return;
  int l = i / (GP*KPH);
  int r2 = i - l*(GP*KPH);
  int prow = r2 / KPH;
  int k = r2 - prow*KPH;
  const float* wihl = (l == 0) ? wih0 : ((l == 1) ? wih1 : wih2);
  const float* whhl = (l == 0) ? whh0 : ((l == 1) ? whh1 : whh2);
  int g = prow / EP, e = prow - g*EP;
  float vh = 0.f;
  if (e < HH && k < HH) vh = whhl[(size_t)(g*HH + e)*HH + k];
  whh16[((size_t)l*GP + prow)*KPH + k] = (_Float16)vh;
  if (prow < GG) {
    float vi = 0.f;
    if (l == 0) { if (k < 40) vi = wihl[(size_t)prow*40 + k]; }
    else        { if (k < HH) vi = wihl[(size_t)prow*HH + k]; }
    wih16[((size_t)l*GG + prow)*KPH + k] = (_Float16)vi;
  }
}

// ---------------------------------------------------------------------------
// batch-major input GEMM: one (l, bg, 8-t slice). 704 thr (11 waves).
// Per t: A=[16b x K] (LDS, row stride 100 dw), B=W_ih; D m=quad*4+r=batch,
// n=n15 -> gx[t][nt*16+n15][quad*4..+3] = one uint2 store.
// ---------------------------------------------------------------------------
__device__ __forceinline__ void gemm_body(
    int l, int bg, int ts, int ch, const int* lengths, const float* x,
    const uint32_t* wihw, const uint32_t* hring, uint16_t* gxs,
    uint32_t* smem, int tid) {
  int maxlen = 1;
  #pragma unroll
  for (int bi = 0; bi < 16; ++bi) {
    int L = lengths[bg*16 + bi]; if (L < 1) L = 1; if (L > TT) L = TT;
    if (L > maxlen) maxlen = L;
  }
  const int tb = ts*TSL;                        // local t base within chunk
  const int t0 = ch*CC + tb;                    // absolute t base
  if (t0 >= maxlen) return;
  int tcnt = maxlen - t0; if (tcnt > TSL) tcnt = TSL;

  // ---- stage A: [TSL][16 batches][100 dw] (halves zero-padded to K) ----
  if (l == 0) {
    for (int idx = tid; idx < TSL*16*32; idx += 704) {
      int tloc = idx >> 9, r = idx & 511, b = r >> 5, dw = r & 31;
      uint32_t v = 0;
      if (dw < 20) {
        const float* xs = x + ((size_t)(bg*16 + b)*TT + (t0 + tloc))*40 + dw*2;
        half2v pp; pp[0] = (_Float16)xs[0]; pp[1] = (_Float16)xs[1];
        v = __builtin_bit_cast(uint32_t, pp);
      }
      smem[(tloc*16 + b)*100 + dw] = v;
    }
  } else {
    const uint32_t* hbs = hring + ((size_t)((l-1)*2 + (ch & 1))*BB)*CC*96;
    for (int idx = tid; idx < TSL*16*96; idx += 704) {
      int tloc = idx / 1536, r = idx - tloc*1536, b = r / 96, dw = r - b*96;
      smem[(tloc*16 + b)*100 + dw] =
          hbs[((size_t)(bg*16 + b)*CC + tb + tloc)*96 + dw];
    }
  }
  __syncthreads();

  const int lane = tid & 63, wv = tid >> 6;
  const int quad = lane >> 4, n15 = lane & 15;
  const int Kt = (l == 0) ? 2 : 6;
  uint16_t* gxo = gxs + ((size_t)(l*4 + bg)*CC + tb)*GG*16;

  for (int tloc = 0; tloc < tcnt; ++tloc) {
    const half8* asrc = (const half8*)(smem + tloc*1600); // batch stride 25 h8
    for (int nt = wv; nt < 41; nt += 11) {
      int wrow = nt*16 + n15;
      const half8* bsrc = (const half8*)(wihw + ((size_t)l*GG + wrow)*KPD);
      f32x4 a0 = {0.f,0.f,0.f,0.f};
      for (int kk = 0; kk < Kt; ++kk) {
        half8 bf = bsrc[kk*4 + quad];
        half8 af = asrc[n15*25 + kk*4 + quad];
        a0 = __builtin_amdgcn_mfma_f32_16x16x32_f16(af, bf, a0, 0, 0, 0);
      }
      half2v p0; p0[0] = (_Float16)a0[0]; p0[1] = (_Float16)a0[1];
      half2v p1; p1[0] = (_Float16)a0[2]; p1[1] = (_Float16)a0[3];
      uint2 pk;
      pk.x = __builtin_bit_cast(uint32_t, p0);
      pk.y = __builtin_bit_cast(uint32_t, p1);
      *(uint2*)(gxo + ((size_t)tloc*GG + wrow)*16 + quad*4) = pk;
    }
  }
}

// ---------------------------------------------------------------------------
// MFMA recurrence body for one (l, batch-group of 16, chunk). 704 thr.
// wave wv owns elements e = 16wv..16wv+15; lane (n15,quad) holds all 4 gates
// of element e = 16wv+n15 for batches quad*4+r in acc[g][r].
// ---------------------------------------------------------------------------
__device__ __forceinline__ void rec_body(
    int l, int bg, int ch, const int* lengths,
    const float* b0, const float* b1, const float* b2,
    const uint32_t* whhw, const uint16_t* gxs, uint32_t* hring,
    float* state_c, uint32_t* state_h, uint32_t* smem, int tid) {

  int maxlen = 1;
  #pragma unroll
  for (int bi = 0; bi < 16; ++bi) {
    int L = lengths[bg*16 + bi]; if (L < 1) L = 1; if (L > TT) L = TT;
    if (L > maxlen) maxlen = L;
  }
  const int t0 = ch*CC;
  if (t0 >= maxlen) return;                     // group fully frozen
  int t1 = t0 + CC; if (t1 > maxlen) t1 = maxlen;

  const int wv = tid >> 6, ln = tid & 63;
  const int quad = ln >> 4, n15 = ln & 15;
  const int e = wv*16 + n15;                    // 0..175
  const int evalid = (e < HH);

  int lenv[4];
  #pragma unroll
  for (int r = 0; r < 4; ++r) {
    int L = lengths[bg*16 + quad*4 + r]; if (L < 1) L = 1; if (L > TT) L = TT;
    lenv[r] = L;
  }

  // resident W_hh fragments: 4 gates x 6 k-steps, half8 each (96 dwords)
  half8 wB[24];
  {
    const half8* wb8 = (const half8*)(whhw + (size_t)l*GP*KPD);
    #pragma unroll
    for (int g = 0; g < 4; ++g) {
      int row = g*EP + e;
      #pragma unroll
      for (int kk = 0; kk < 6; ++kk)
        wB[g*6 + kk] = wb8[(size_t)row*24 + kk*4 + quad];
    }
  }
  const float* bp = (l == 0) ? b0 : ((l == 1) ? b1 : b2);
  float bias[4];
  #pragma unroll
  for (int g = 0; g < 4; ++g) bias[g] = evalid ? bp[g*HH + e] : 0.f;

  float creg[4] = {0.f, 0.f, 0.f, 0.f};
  if (ch > 0 && evalid) {
    #pragma unroll
    for (int r = 0; r < 4; ++r)
      creg[r] = state_c[((size_t)l*BB + bg*16 + quad*4 + r)*HH + e];
  }

  // h double buffer in LDS: [16 batches][100 dwords], halves 164..191 = 0
  uint32_t* hb0 = smem;
  uint32_t* hb1 = smem + 1600;
  for (int i2 = tid; i2 < 1600; i2 += 704) {
    int bb = i2 / 100, dd = i2 - bb*100;
    uint32_t v = 0;
    if (dd < 96 && ch > 0) v = state_h[((size_t)l*BB + bg*16 + bb)*96 + dd];
    hb0[i2] = v; hb1[i2] = v;
  }
  __syncthreads();

  // per-lane h bits for its 4 (batch, e) slots (re-published every step so
  // frozen sequences keep valid h in BOTH buffers)
  uint16_t hbits[4];
  #pragma unroll
  for (int r = 0; r < 4; ++r)
    hbits[r] = ((const uint16_t*)hb0)[(quad*4 + r)*200 + e];

  uint32_t* hrb = (l < 2)
      ? hring + ((size_t)(l*2 + (ch & 1))*BB)*CC*96 : (uint32_t*)0;
  const uint16_t* gxb = gxs + ((size_t)(l*4 + bg)*CC)*GG*16;
  uint32_t* shb = state_h + ((size_t)l*BB + bg*16)*96;

  uint2 gxp[4] = {};
  if (evalid) {
    #pragma unroll
    for (int g = 0; g < 4; ++g)
      gxp[g] = *(const uint2*)(gxb + ((size_t)g*HH + e)*16 + quad*4);
  }

  int p = 0;
  for (int t = t0; t < t1; ++t) {
    uint32_t* hin  = p ? hb1 : hb0;
    uint32_t* hout = p ? hb0 : hb1;

    // acc init = bias + gx (this step's input projection)
    f32x4 acc[4];
    #pragma unroll
    for (int g = 0; g < 4; ++g) {
      const _Float16* gh = (const _Float16*)&gxp[g];
      #pragma unroll
      for (int r = 0; r < 4; ++r) acc[g][r] = bias[g] + (float)gh[r];
    }
    // prefetch next step's gx (hidden under MFMA + update)
    if (t + 1 < t1 && evalid) {
      int trow = t + 1 - t0;
      #pragma unroll
      for (int g = 0; g < 4; ++g)
        gxp[g] = *(const uint2*)(gxb + ((size_t)trow*GG + g*HH + e)*16 + quad*4);
    }
    // recurrent projection: [16x164] @ W_hh^T, 24 MFMA
    #pragma unroll
    for (int kk = 0; kk < 6; ++kk) {
      half8 af = *(const half8*)&hin[n15*100 + kk*16 + quad*4];
      acc[0] = __builtin_amdgcn_mfma_f32_16x16x32_f16(af, wB[kk],      acc[0], 0, 0, 0);
      acc[1] = __builtin_amdgcn_mfma_f32_16x16x32_f16(af, wB[6 + kk],  acc[1], 0, 0, 0);
      acc[2] = __builtin_amdgcn_mfma_f32_16x16x32_f16(af, wB[12 + kk], acc[2], 0, 0, 0);
      acc[3] = __builtin_amdgcn_mfma_f32_16x16x32_f16(af, wB[18 + kk], acc[3], 0, 0, 0);
    }
    // ring publish h(t-1) from hin
    if (hrb && t > t0) {
      int row = t - 1 - t0;
      for (int i2 = tid; i2 < 1536; i2 += 704) {
        int bb = i2 / 96, dd = i2 - bb*96;
        hrb[((size_t)(bg*16 + bb)*CC + row)*96 + dd] = hin[bb*100 + dd];
      }
    }
    // cell update: lane has gates i,f,g,o of element e for 4 batches
    #pragma unroll
    for (int r = 0; r < 4; ++r) {
      float gi = acc[0][r], gf = acc[1][r], gg2 = acc[2][r], go = acc[3][r];
      float cn = sigmf(gf)*creg[r] + sigmf(gi)*tanhf_(gg2);
      float hv = sigmf(go)*tanhf_(cn);
      if (t < lenv[r]) {                        // per-batch freeze
        creg[r] = cn;
        _Float16 h16 = (_Float16)hv;
        hbits[r] = __builtin_bit_cast(uint16_t, h16);
      }
      if (evalid)
        ((uint16_t*)hout)[(quad*4 + r)*200 + e] = hbits[r];
    }
    __syncthreads();                            // hout visible
    p ^= 1;
  }

  // final ring publish + persist state
  uint32_t* hfin = p ? hb1 : hb0;
  {
    int rowl = t1 - 1 - t0;
    for (int i2 = tid; i2 < 1536; i2 += 704) {
      int bb = i2 / 96, dd = i2 - bb*96;
      uint32_t v = hfin[bb*100 + dd];
      if (hrb) hrb[((size_t)(bg*16 + bb)*CC + rowl)*96 + dd] = v;
      shb[(size_t)bb*96 + dd] = v;
    }
  }
  if (evalid) {
    #pragma unroll
    for (int r = 0; r < 4; ++r)
      state_c[((size_t)l*BB + bg*16 + quad*4 + r)*HH + e] = creg[r];
  }
}

// ---------------------------------------------------------------------------
// fused step: blocks 0..191 = gemm(l, bg, tslice, ch=j-2l),
//             blocks 192..203 = rec(l, bg, ch=j-2l-1)
// gx double-buffered by chunk parity.
// ---------------------------------------------------------------------------
__global__ __launch_bounds__(704) void kstep_f(
    int j, const int* lengths, const float* x,
    const uint32_t* wihw, const uint32_t* whhw,
    const float* b0, const float* b1, const float* b2,
    uint16_t* gx, uint32_t* hring, float* state_c, uint32_t* state_h) {
  __shared__ __align__(16) uint32_t smem[TSL*1600];     // 51.2 KB
  const int blk = blockIdx.x, tid = threadIdx.x;
  if (blk < 192) {
    const int l = blk >> 6, r = blk & 63, bg = r >> 4, ts = r & 15;
    const int ch = j - 2*l;
    if (ch < 0 || ch >= NCH) return;
    uint16_t* gxs = gx + (size_t)(ch & 1)*GX_SLOT_HALVES;
    gemm_body(l, bg, ts, ch, lengths, x, wihw, hring, gxs, smem, tid);
  } else {
    const int idx = blk - 192;
    if (idx >= 12) return;
    const int l = idx >> 2, bg = idx & 3;
    const int ch = j - 2*l - 1;
    if (ch < 0 || ch >= NCH) return;
    const uint16_t* gxs = gx + (size_t)(ch & 1)*GX_SLOT_HALVES;
    rec_body(l, bg, ch, lengths, b0, b1, b2, whhw, gxs, hring,
             state_c, state_h, smem, tid);
  }
}

// ---- sequential fallback (1 gx slot; gemm(i) then rec(i) each iteration) ----
__global__ __launch_bounds__(704) void kgemm_s(
    int step, const int* lengths, const float* x,
    const uint32_t* wihw, uint16_t* gx, const uint32_t* hring) {
  __shared__ __align__(16) uint32_t smem[TSL*1600];
  const int blk = blockIdx.x;
  const int l = blk >> 6, r = blk & 63, bg = r >> 4, ts = r & 15;
  const int ch = step - l;
  if (ch < 0 || ch >= NCH) return;
  gemm_body(l, bg, ts, ch, lengths, x, wihw, hring, gx, smem, threadIdx.x);
}

__global__ __launch_bounds__(704) void krec_s(
    int step, const int* lengths,
    const float* b0, const float* b1, const float* b2,
    const uint32_t* whhw, const uint16_t* gx, uint32_t* hring,
    float* state_c, uint32_t* state_h) {
  __shared__ __align__(16) uint32_t smem[TSL*1600];
  const int idx = blockIdx.x;
  const int l = idx >> 2, bg = idx & 3;
  const int ch = step - l;
  if (ch < 0 || ch >= NCH) return;
  rec_body(l, bg, ch, lengths, b0, b1, b2, whhw, gx, hring,
           state_c, state_h, smem, threadIdx.x);
}

// ---------------------------------------------------------------------------
// FC epilogue on layer-2 final hidden state
// ---------------------------------------------------------------------------
__global__ void kfc(const float* fcw, const float* fcb,
                    const uint32_t* state_h, float* out) {
  int b = blockIdx.x, o = threadIdx.x;
  if (o >= 7) return;
  const uint16_t* h16 = (const uint16_t*)(state_h + (size_t)(2*BB + b)*96);
  float s = fcb[o];
  for (int m = 0; m < HH; ++m) {
    _Float16 hv = __builtin_bit_cast(_Float16, h16[m]);
    s += fcw[o*HH + m] * (float)hv;
  }
  out[b*7 + o] = s;
}

// ---------------------------------------------------------------------------
extern "C" void kernel_launch(void* const* d_in, const int* in_sizes, int n_in,
                              void* d_out, int out_size, void* d_ws, size_t ws_size,
                              hipStream_t stream) {
  const float* x      = (const float*)d_in[0];
  const int*  lengths = (const int*)  d_in[1];
  const float* wih0   = (const float*)d_in[2];
  const float* whh0   = (const float*)d_in[3];
  const float* b0     = (const float*)d_in[4];
  const float* wih1   = (const float*)d_in[5];
  const float* whh1   = (const float*)d_in[6];
  const float* b1     = (const float*)d_in[7];
  const float* wih2   = (const float*)d_in[8];
  const float* whh2   = (const float*)d_in[9];
  const float* b2     = (const float*)d_in[10];
  const float* fcw    = (const float*)d_in[11];
  const float* fcb    = (const float*)d_in[12];

  const size_t off_wih = 0;
  const size_t off_whh = SZ_WIH;
  const size_t off_gx  = SZ_WIH + SZ_WHH;
  const size_t tail    = SZ_HR + SZ_SC + SZ_SH;
  const size_t need_fused = off_gx + 2*SZ_GX1 + tail;   // ~78.8 MB
  const size_t need_seq   = off_gx + 1*SZ_GX1 + tail;   // ~46.6 MB
  const int fused = (ws_size >= need_fused);
  if (!fused && ws_size < need_seq) return;             // loud, clean failure
  const size_t gx_bytes = fused ? 2*SZ_GX1 : SZ_GX1;
  const size_t off_hr = off_gx + gx_bytes;
  const size_t off_sc = off_hr + SZ_HR;
  const size_t off_sh = off_sc + SZ_SC;

  char* ws = (char*)d_ws;
  _Float16* wih16 = (_Float16*)(ws + off_wih);
  _Float16* whh16 = (_Float16*)(ws + off_whh);
  uint16_t* gxw   = (uint16_t*)(ws + off_gx);
  uint32_t* hrw   = (uint32_t*)(ws + off_hr);
  float*    scw   = (float*)   (ws + off_sc);
  uint32_t* shw   = (uint32_t*)(ws + off_sh);

  hipLaunchKernelGGL(kprep_w, dim3((3*GP*KPH + 255)/256), dim3(256), 0, stream,
                     wih0, whh0, wih1, whh1, wih2, whh2, wih16, whh16);

  if (fused) {
    for (int jj = 0; jj <= NCH + 4; ++jj) {             // j = 0..20
      hipLaunchKernelGGL(kstep_f, dim3(204), dim3(704), 0, stream,
                         jj, lengths, x, (const uint32_t*)wih16,
                         (const uint32_t*)whh16, b0, b1, b2,
                         gxw, hrw, scw, shw);
    }
  } else {
    for (int i = 0; i < NCH + 2; ++i) {
      hipLaunchKernelGGL(kgemm_s, dim3(192), dim3(704), 0, stream,
                         i, lengths, x, (const uint32_t*)wih16, gxw,
                         (const uint32_t*)hrw);
      hipLaunchKernelGGL(krec_s, dim3(12), dim3(704), 0, stream,
                         i, lengths, b0, b1, b2, (const uint32_t*)whh16,
                         (const uint16_t*)gxw, hrw, scw, shw);
    }
  }

  hipLaunchKernelGGL(kfc, dim3(64), dim3(64), 0, stream,
                     fcw, fcb, shw, (float*)d_out);
}

// Round 4
// 6856.776 us; speedup vs baseline: 1.3632x; 1.3579x over previous
//
#include <hip/hip_runtime.h>
#include <stdint.h>

// ---------------------------------------------------------------------------
// 3-layer packed-sequence LSTM, B=64 T=2048 D=40 H=164, FC->7. fp32 in/out.
//
// v5: kill the W_hh register spill (v3/v4's 490us was scratch-reload bound:
//     VGPR_Count=84 vs ~160 needed -> wB[24] spilled, every MFMA operand
//     re-read from scratch/L2 each step).
//
//  * __launch_bounds__(704, 3): 3 waves/EU -> VGPR cap ~168 -> W_hh frags
//    stay register-resident (96 VGPR/lane). 11-wave block still launches
//    (3 waves/SIMD x 168 <= 512).
//  * bias folded into gx at gemm time (rec acc init = gx only).
//  * gemm: W_ih fragments + bias hoisted out of the t-loop, A-frags hoisted
//    per t; unified static K-loop (l=0 zero-pads A in LDS) so all register
//    arrays are statically indexed (no scratch).
//  * rec step barrier = s_waitcnt lgkmcnt(0) + s_barrier (no vmcnt drain;
//    ring stores / gx prefetch float across steps; all cross-wave data is
//    LDS double-buffered).
//  Structure (staircase, gx parity double-buffer, batch-major gx) unchanged
//  from v4 (passed, write amplification already fixed).
// ---------------------------------------------------------------------------

#define TT 2048
#define BB 64
#define GG 656   // 4*H (compact gate rows)
#define HH 164
#define EP 176   // padded elems per gate (16-aligned)
#define GP 704   // 4*EP padded gate rows
#define KPH 192  // K padded to 192 halves
#define KPD 96   // = KPH/2 dwords
#define CC 128   // chunk timesteps
#define NCH (TT/CC)   // 16
#define TSL 8    // timesteps per gemm slice block
#define NSL (CC/TSL)  // 16 slices

typedef _Float16 half2v __attribute__((ext_vector_type(2)));
typedef _Float16 half8  __attribute__((ext_vector_type(8)));
typedef float    f32x4  __attribute__((ext_vector_type(4)));

// ---- workspace layout (bytes) ----
#define SZ_WIH   ((size_t)3*GG*KPH*2)          // f16 [3][656][192]
#define SZ_WHH   ((size_t)3*GP*KPH*2)          // f16 [3][704][192]
#define SZ_GX1   ((size_t)3*4*CC*GG*16*2)      // f16 [3][4][128][656][16] ~32.2MB
#define GX_SLOT_HALVES ((size_t)3*4*CC*GG*16)
#define SZ_HR    ((size_t)2*2*BB*CC*96*4)      // dw [2l][2slot][64][128][96]
#define SZ_SC    ((size_t)3*BB*HH*4)           // f32 c-state
#define SZ_SH    ((size_t)3*BB*96*4)           // dword h-state (f16 pairs)

__device__ __forceinline__ float sigmf(float x) { return 1.0f/(1.0f + __expf(-x)); }
__device__ __forceinline__ float tanhf_(float x) { return 2.0f/(1.0f + __expf(-2.0f*x)) - 1.0f; }

// ---------------------------------------------------------------------------
// weight prep: wih compact [3][656][192] (K zero-padded), whh padded
// [3][704][192] (rows g*176+e, zero for e>=164; K zero-padded)
// ---------------------------------------------------------------------------
__global__ void kprep_w(const float* wih0, const float* whh0,
                        const float* wih1, const float* whh1,
                        const float* wih2, const float* whh2,
                        _Float16* wih16, _Float16* whh16) {
  int i = threadIdx.x + blockIdx.x * blockDim.x;
  if (i >= 3*GP*KPH) return;
  int l = i / (GP*KPH);
  int r2 = i - l*(GP*KPH);
  int prow = r2 / KPH;
  int k = r2 - prow*KPH;
  const float* wihl = (l == 0) ? wih0 : ((l == 1) ? wih1 : wih2);
  const float* whhl = (l == 0) ? whh0 : ((l == 1) ? whh1 : whh2);
  int g = prow / EP, e = prow - g*EP;
  float vh = 0.f;
  if (e < HH && k < HH) vh = whhl[(size_t)(g*HH + e)*HH + k];
  whh16[((size_t)l*GP + prow)*KPH + k] = (_Float16)vh;
  if (prow < GG) {
    float vi = 0.f;
    if (l == 0) { if (k < 40) vi = wihl[(size_t)prow*40 + k]; }
    else        { if (k < HH) vi = wihl[(size_t)prow*HH + k]; }
    wih16[((size_t)l*GG + prow)*KPH + k] = (_Float16)vi;
  }
}

// ---------------------------------------------------------------------------
// batch-major input GEMM: one (l, bg, 8-t slice). 704 thr (11 waves).
// Per t: A=[16b x K] (LDS, row stride 100 dw), B=W_ih; D m=quad*4+r=batch,
// n=n15 -> gx[t][nt*16+n15][quad*4..+3] = one uint2 store. Bias folded in.
// ---------------------------------------------------------------------------
__device__ __forceinline__ void gemm_body(
    int l, int bg, int ts, int ch, const int* lengths, const float* x,
    const uint32_t* wihw, const uint32_t* hring, const float* bp,
    uint16_t* gxs, uint32_t* smem, int tid) {
  int maxlen = 1;
  #pragma unroll
  for (int bi = 0; bi < 16; ++bi) {
    int L = lengths[bg*16 + bi]; if (L < 1) L = 1; if (L > TT) L = TT;
    if (L > maxlen) maxlen = L;
  }
  const int tb = ts*TSL;                        // local t base within chunk
  const int t0 = ch*CC + tb;                    // absolute t base
  if (t0 >= maxlen) return;
  int tcnt = maxlen - t0; if (tcnt > TSL) tcnt = TSL;

  // ---- stage A: [TSL][16 batches][100 dw], full 96 dw (zeros pad K) ----
  if (l == 0) {
    for (int idx = tid; idx < TSL*16*96; idx += 704) {
      int tloc = idx / 1536, r = idx - tloc*1536, b = r / 96, dw = r - b*96;
      uint32_t v = 0;
      if (dw < 20) {
        const float* xs = x + ((size_t)(bg*16 + b)*TT + (t0 + tloc))*40 + dw*2;
        half2v pp; pp[0] = (_Float16)xs[0]; pp[1] = (_Float16)xs[1];
        v = __builtin_bit_cast(uint32_t, pp);
      }
      smem[(tloc*16 + b)*100 + dw] = v;
    }
  } else {
    const uint32_t* hbs = hring + ((size_t)((l-1)*2 + (ch & 1))*BB)*CC*96;
    for (int idx = tid; idx < TSL*16*96; idx += 704) {
      int tloc = idx / 1536, r = idx - tloc*1536, b = r / 96, dw = r - b*96;
      smem[(tloc*16 + b)*100 + dw] =
          hbs[((size_t)(bg*16 + b)*CC + tb + tloc)*96 + dw];
    }
  }
  __syncthreads();

  const int lane = tid & 63, wv = tid >> 6;
  const int quad = lane >> 4, n15 = lane & 15;
  uint16_t* gxo = gxs + ((size_t)(l*4 + bg)*CC + tb)*GG*16;

  // ---- hoisted W_ih fragments + bias (static indices; regs) ----
  half8 wf[4][6];
  float bv[4] = {0.f, 0.f, 0.f, 0.f};
  #pragma unroll
  for (int ni = 0; ni < 4; ++ni) {
    int nt = wv + ni*11;
    if (nt < 41) {
      int wrow = nt*16 + n15;
      const half8* bsrc = (const half8*)(wihw + ((size_t)l*GG + wrow)*KPD);
      #pragma unroll
      for (int kk = 0; kk < 6; ++kk) wf[ni][kk] = bsrc[kk*4 + quad];
      bv[ni] = bp[wrow];
    }
  }

  for (int tloc = 0; tloc < tcnt; ++tloc) {
    const half8* asrc = (const half8*)(smem + tloc*1600); // batch stride 25 h8
    half8 af[6];
    #pragma unroll
    for (int kk = 0; kk < 6; ++kk) af[kk] = asrc[n15*25 + kk*4 + quad];
    #pragma unroll
    for (int ni = 0; ni < 4; ++ni) {
      int nt = wv + ni*11;
      if (nt < 41) {
        int wrow = nt*16 + n15;
        f32x4 a0 = {0.f,0.f,0.f,0.f};
        #pragma unroll
        for (int kk = 0; kk < 6; ++kk)
          a0 = __builtin_amdgcn_mfma_f32_16x16x32_f16(af[kk], wf[ni][kk], a0, 0, 0, 0);
        half2v p0; p0[0] = (_Float16)(a0[0] + bv[ni]); p0[1] = (_Float16)(a0[1] + bv[ni]);
        half2v p1; p1[0] = (_Float16)(a0[2] + bv[ni]); p1[1] = (_Float16)(a0[3] + bv[ni]);
        uint2 pk;
        pk.x = __builtin_bit_cast(uint32_t, p0);
        pk.y = __builtin_bit_cast(uint32_t, p1);
        *(uint2*)(gxo + ((size_t)tloc*GG + wrow)*16 + quad*4) = pk;
      }
    }
  }
}

// ---------------------------------------------------------------------------
// MFMA recurrence body for one (l, batch-group of 16, chunk). 704 thr.
// wave wv owns elements e = 16wv..16wv+15; lane (n15,quad) holds all 4 gates
// of element e = 16wv+n15 for batches quad*4+r in acc[g][r].
// ---------------------------------------------------------------------------
__device__ __forceinline__ void rec_body(
    int l, int bg, int ch, const int* lengths,
    const uint32_t* whhw, const uint16_t* gxs, uint32_t* hring,
    float* state_c, uint32_t* state_h, uint32_t* smem, int tid) {

  int maxlen = 1;
  #pragma unroll
  for (int bi = 0; bi < 16; ++bi) {
    int L = lengths[bg*16 + bi]; if (L < 1) L = 1; if (L > TT) L = TT;
    if (L > maxlen) maxlen = L;
  }
  const int t0 = ch*CC;
  if (t0 >= maxlen) return;                     // group fully frozen
  int t1 = t0 + CC; if (t1 > maxlen) t1 = maxlen;

  const int wv = tid >> 6, ln = tid & 63;
  const int quad = ln >> 4, n15 = ln & 15;
  const int e = wv*16 + n15;                    // 0..175
  const int evalid = (e < HH);

  int lenv[4];
  #pragma unroll
  for (int r = 0; r < 4; ++r) {
    int L = lengths[bg*16 + quad*4 + r]; if (L < 1) L = 1; if (L > TT) L = TT;
    lenv[r] = L;
  }

  // resident W_hh fragments: 4 gates x 6 k-steps, half8 each (96 VGPRs)
  half8 wB[24];
  {
    const half8* wb8 = (const half8*)(whhw + (size_t)l*GP*KPD);
    #pragma unroll
    for (int g = 0; g < 4; ++g) {
      int row = g*EP + e;
      #pragma unroll
      for (int kk = 0; kk < 6; ++kk)
        wB[g*6 + kk] = wb8[(size_t)row*24 + kk*4 + quad];
    }
  }

  float creg[4] = {0.f, 0.f, 0.f, 0.f};
  if (ch > 0 && evalid) {
    #pragma unroll
    for (int r = 0; r < 4; ++r)
      creg[r] = state_c[((size_t)l*BB + bg*16 + quad*4 + r)*HH + e];
  }

  // h double buffer in LDS: [16 batches][100 dwords], halves 164..191 = 0
  uint32_t* hb0 = smem;
  uint32_t* hb1 = smem + 1600;
  for (int i2 = tid; i2 < 1600; i2 += 704) {
    int bb = i2 / 100, dd = i2 - bb*100;
    uint32_t v = 0;
    if (dd < 96 && ch > 0) v = state_h[((size_t)l*BB + bg*16 + bb)*96 + dd];
    hb0[i2] = v; hb1[i2] = v;
  }
  __syncthreads();

  // per-lane h bits for its 4 (batch, e) slots (re-published every step so
  // frozen sequences keep valid h in BOTH buffers)
  uint16_t hbits[4];
  #pragma unroll
  for (int r = 0; r < 4; ++r)
    hbits[r] = ((const uint16_t*)hb0)[(quad*4 + r)*200 + e];

  uint32_t* hrb = (l < 2)
      ? hring + ((size_t)(l*2 + (ch & 1))*BB)*CC*96 : (uint32_t*)0;
  const uint16_t* gxb = gxs + ((size_t)(l*4 + bg)*CC)*GG*16;
  uint32_t* shb = state_h + ((size_t)l*BB + bg*16)*96;

  uint2 gxp[4] = {};
  if (evalid) {
    #pragma unroll
    for (int g = 0; g < 4; ++g)
      gxp[g] = *(const uint2*)(gxb + ((size_t)g*HH + e)*16 + quad*4);
  }

  int p = 0;
  for (int t = t0; t < t1; ++t) {
    uint32_t* hin  = p ? hb1 : hb0;
    uint32_t* hout = p ? hb0 : hb1;

    // acc init = gx (bias already folded in by gemm)
    f32x4 acc[4];
    #pragma unroll
    for (int g = 0; g < 4; ++g) {
      const _Float16* gh = (const _Float16*)&gxp[g];
      #pragma unroll
      for (int r = 0; r < 4; ++r) acc[g][r] = (float)gh[r];
    }
    // prefetch next step's gx (hidden under MFMA + update)
    if (t + 1 < t1 && evalid) {
      int trow = t + 1 - t0;
      #pragma unroll
      for (int g = 0; g < 4; ++g)
        gxp[g] = *(const uint2*)(gxb + ((size_t)trow*GG + g*HH + e)*16 + quad*4);
    }
    // recurrent projection: [16x164] @ W_hh^T, 24 MFMA
    #pragma unroll
    for (int kk = 0; kk < 6; ++kk) {
      half8 af = *(const half8*)&hin[n15*100 + kk*16 + quad*4];
      acc[0] = __builtin_amdgcn_mfma_f32_16x16x32_f16(af, wB[kk],      acc[0], 0, 0, 0);
      acc[1] = __builtin_amdgcn_mfma_f32_16x16x32_f16(af, wB[6 + kk],  acc[1], 0, 0, 0);
      acc[2] = __builtin_amdgcn_mfma_f32_16x16x32_f16(af, wB[12 + kk], acc[2], 0, 0, 0);
      acc[3] = __builtin_amdgcn_mfma_f32_16x16x32_f16(af, wB[18 + kk], acc[3], 0, 0, 0);
    }
    // ring publish h(t-1) from hin
    if (hrb && t > t0) {
      int row = t - 1 - t0;
      for (int i2 = tid; i2 < 1536; i2 += 704) {
        int bb = i2 / 96, dd = i2 - bb*96;
        hrb[((size_t)(bg*16 + bb)*CC + row)*96 + dd] = hin[bb*100 + dd];
      }
    }
    // cell update: lane has gates i,f,g,o of element e for 4 batches
    #pragma unroll
    for (int r = 0; r < 4; ++r) {
      float gi = acc[0][r], gf = acc[1][r], gg2 = acc[2][r], go = acc[3][r];
      float cn = sigmf(gf)*creg[r] + sigmf(gi)*tanhf_(gg2);
      float hv = sigmf(go)*tanhf_(cn);
      if (t < lenv[r]) {                        // per-batch freeze
        creg[r] = cn;
        _Float16 h16 = (_Float16)hv;
        hbits[r] = __builtin_bit_cast(uint16_t, h16);
      }
      if (evalid)
        ((uint16_t*)hout)[(quad*4 + r)*200 + e] = hbits[r];
    }
    // lgkm-only barrier: no vmcnt drain (ring stores / gx prefetch float).
    // All cross-wave data in this loop is LDS (hbuf), covered by lgkmcnt.
    asm volatile("s_waitcnt lgkmcnt(0)" ::: "memory");
    __builtin_amdgcn_s_barrier();
    p ^= 1;
  }

  // final ring publish + persist state
  uint32_t* hfin = p ? hb1 : hb0;
  {
    int rowl = t1 - 1 - t0;
    for (int i2 = tid; i2 < 1536; i2 += 704) {
      int bb = i2 / 96, dd = i2 - bb*96;
      uint32_t v = hfin[bb*100 + dd];
      if (hrb) hrb[((size_t)(bg*16 + bb)*CC + rowl)*96 + dd] = v;
      shb[(size_t)bb*96 + dd] = v;
    }
  }
  if (evalid) {
    #pragma unroll
    for (int r = 0; r < 4; ++r)
      state_c[((size_t)l*BB + bg*16 + quad*4 + r)*HH + e] = creg[r];
  }
}

// ---------------------------------------------------------------------------
// fused step: blocks 0..191 = gemm(l, bg, tslice, ch=j-2l),
//             blocks 192..203 = rec(l, bg, ch=j-2l-1)
// gx double-buffered by chunk parity.
// ---------------------------------------------------------------------------
__global__ __launch_bounds__(704, 3) void kstep_f(
    int j, const int* lengths, const float* x,
    const uint32_t* wihw, const uint32_t* whhw,
    const float* b0, const float* b1, const float* b2,
    uint16_t* gx, uint32_t* hring, float* state_c, uint32_t* state_h) {
  __shared__ __align__(16) uint32_t smem[TSL*1600];     // 51.2 KB
  const int blk = blockIdx.x, tid = threadIdx.x;
  if (blk < 192) {
    const int l = blk >> 6, r = blk & 63, bg = r >> 4, ts = r & 15;
    const int ch = j - 2*l;
    if (ch < 0 || ch >= NCH) return;
    const float* bp = (l == 0) ? b0 : ((l == 1) ? b1 : b2);
    uint16_t* gxs = gx + (size_t)(ch & 1)*GX_SLOT_HALVES;
    gemm_body(l, bg, ts, ch, lengths, x, wihw, hring, bp, gxs, smem, tid);
  } else {
    const int idx = blk - 192;
    if (idx >= 12) return;
    const int l = idx >> 2, bg = idx & 3;
    const int ch = j - 2*l - 1;
    if (ch < 0 || ch >= NCH) return;
    const uint16_t* gxs = gx + (size_t)(ch & 1)*GX_SLOT_HALVES;
    rec_body(l, bg, ch, lengths, whhw, gxs, hring,
             state_c, state_h, smem, tid);
  }
}

// ---- sequential fallback (1 gx slot; gemm(i) then rec(i) each iteration) ----
__global__ __launch_bounds__(704, 3) void kgemm_s(
    int step, const int* lengths, const float* x,
    const uint32_t* wihw, const float* b0, const float* b1, const float* b2,
    uint16_t* gx, const uint32_t* hring) {
  __shared__ __align__(16) uint32_t smem[TSL*1600];
  const int blk = blockIdx.x;
  const int l = blk >> 6, r = blk & 63, bg = r >> 4, ts = r & 15;
  const int ch = step - l;
  if (ch < 0 || ch >= NCH) return;
  const float* bp = (l == 0) ? b0 : ((l == 1) ? b1 : b2);
  gemm_body(l, bg, ts, ch, lengths, x, wihw, hring, bp, gx, smem, threadIdx.x);
}

__global__ __launch_bounds__(704, 3) void krec_s(
    int step, const int* lengths,
    const uint32_t* whhw, const uint16_t* gx, uint32_t* hring,
    float* state_c, uint32_t* state_h) {
  __shared__ __align__(16) uint32_t smem[TSL*1600];
  const int idx = blockIdx.x;
  const int l = idx >> 2, bg = idx & 3;
  const int ch = step - l;
  if (ch < 0 || ch >= NCH) return;
  rec_body(l, bg, ch, lengths, whhw, gx, hring,
           state_c, state_h, smem, threadIdx.x);
}

// ---------------------------------------------------------------------------
// FC epilogue on layer-2 final hidden state
// ---------------------------------------------------------------------------
__global__ void kfc(const float* fcw, const float* fcb,
                    const uint32_t* state_h, float* out) {
  int b = blockIdx.x, o = threadIdx.x;
  if (o >= 7) return;
  const uint16_t* h16 = (const uint16_t*)(state_h + (size_t)(2*BB + b)*96);
  float s = fcb[o];
  for (int m = 0; m < HH; ++m) {
    _Float16 hv = __builtin_bit_cast(_Float16, h16[m]);
    s += fcw[o*HH + m] * (float)hv;
  }
  out[b*7 + o] = s;
}

// ---------------------------------------------------------------------------
extern "C" void kernel_launch(void* const* d_in, const int* in_sizes, int n_in,
                              void* d_out, int out_size, void* d_ws, size_t ws_size,
                              hipStream_t stream) {
  const float* x      = (const float*)d_in[0];
  const int*  lengths = (const int*)  d_in[1];
  const float* wih0   = (const float*)d_in[2];
  const float* whh0   = (const float*)d_in[3];
  const float* b0     = (const float*)d_in[4];
  const float* wih1   = (const float*)d_in[5];
  const float* whh1   = (const float*)d_in[6];
  const float* b1     = (const float*)d_in[7];
  const float* wih2   = (const float*)d_in[8];
  const float* whh2   = (const float*)d_in[9];
  const float* b2     = (const float*)d_in[10];
  const float* fcw    = (const float*)d_in[11];
  const float* fcb    = (const float*)d_in[12];

  const size_t off_wih = 0;
  const size_t off_whh = SZ_WIH;
  const size_t off_gx  = SZ_WIH + SZ_WHH;
  const size_t tail    = SZ_HR + SZ_SC + SZ_SH;
  const size_t need_fused = off_gx + 2*SZ_GX1 + tail;   // ~78.8 MB
  const size_t need_seq   = off_gx + 1*SZ_GX1 + tail;   // ~46.6 MB
  const int fused = (ws_size >= need_fused);
  if (!fused && ws_size < need_seq) return;             // loud, clean failure
  const size_t gx_bytes = fused ? 2*SZ_GX1 : SZ_GX1;
  const size_t off_hr = off_gx + gx_bytes;
  const size_t off_sc = off_hr + SZ_HR;
  const size_t off_sh = off_sc + SZ_SC;

  char* ws = (char*)d_ws;
  _Float16* wih16 = (_Float16*)(ws + off_wih);
  _Float16* whh16 = (_Float16*)(ws + off_whh);
  uint16_t* gxw   = (uint16_t*)(ws + off_gx);
  uint32_t* hrw   = (uint32_t*)(ws + off_hr);
  float*    scw   = (float*)   (ws + off_sc);
  uint32_t* shw   = (uint32_t*)(ws + off_sh);

  hipLaunchKernelGGL(kprep_w, dim3((3*GP*KPH + 255)/256), dim3(256), 0, stream,
                     wih0, whh0, wih1, whh1, wih2, whh2, wih16, whh16);

  if (fused) {
    for (int jj = 0; jj <= NCH + 4; ++jj) {             // j = 0..20
      hipLaunchKernelGGL(kstep_f, dim3(204), dim3(704), 0, stream,
                         jj, lengths, x, (const uint32_t*)wih16,
                         (const uint32_t*)whh16, b0, b1, b2,
                         gxw, hrw, scw, shw);
    }
  } else {
    for (int i = 0; i < NCH + 2; ++i) {
      hipLaunchKernelGGL(kgemm_s, dim3(192), dim3(704), 0, stream,
                         i, lengths, x, (const uint32_t*)wih16,
                         b0, b1, b2, gxw, (const uint32_t*)hrw);
      hipLaunchKernelGGL(krec_s, dim3(12), dim3(704), 0, stream,
                         i, lengths, (const uint32_t*)whh16,
                         (const uint16_t*)gxw, hrw, scw, shw);
    }
  }

  hipLaunchKernelGGL(kfc, dim3(64), dim3(64), 0, stream,
                     fcw, fcb, shw, (float*)d_out);
}

// Round 5
// 6739.596 us; speedup vs baseline: 1.3869x; 1.0174x over previous
//
#include <hip/hip_runtime.h>
#include <stdint.h>

// ---------------------------------------------------------------------------
// 3-layer packed-sequence LSTM, B=64 T=2048 D=40 H=164, FC->7. fp32 in/out.
//
// v6: fix the REAL spill cause. v5's __launch_bounds__(704,3) forced the
//     compiler to budget for 2 blocks/CU (22 waves, 6/SIMD) -> 85-VGPR cap
//     (observed VGPR_Count=84) -> wB[24] (96 regs) spilled to scratch and
//     was reloaded every timestep (367us/dispatch, ~6900 cy/step).
//     __launch_bounds__(704,1): 1 block/CU, 11 waves (3/3/3/2 per SIMD),
//     cap 512/3 = 170 -> rec body (~166 regs) fits register-resident.
//
//  * also hoisted the ring-publish index divisions out of the step loop.
//  Everything else byte-identical to v5 (passed, absmax 2^-10):
//  batch-major gx, bias folded into gx, staircase fusion, parity dbuf,
//  lgkm-only step barrier.
// ---------------------------------------------------------------------------

#define TT 2048
#define BB 64
#define GG 656   // 4*H (compact gate rows)
#define HH 164
#define EP 176   // padded elems per gate (16-aligned)
#define GP 704   // 4*EP padded gate rows
#define KPH 192  // K padded to 192 halves
#define KPD 96   // = KPH/2 dwords
#define CC 128   // chunk timesteps
#define NCH (TT/CC)   // 16
#define TSL 8    // timesteps per gemm slice block
#define NSL (CC/TSL)  // 16 slices

typedef _Float16 half2v __attribute__((ext_vector_type(2)));
typedef _Float16 half8  __attribute__((ext_vector_type(8)));
typedef float    f32x4  __attribute__((ext_vector_type(4)));

// ---- workspace layout (bytes) ----
#define SZ_WIH   ((size_t)3*GG*KPH*2)          // f16 [3][656][192]
#define SZ_WHH   ((size_t)3*GP*KPH*2)          // f16 [3][704][192]
#define SZ_GX1   ((size_t)3*4*CC*GG*16*2)      // f16 [3][4][128][656][16] ~32.2MB
#define GX_SLOT_HALVES ((size_t)3*4*CC*GG*16)
#define SZ_HR    ((size_t)2*2*BB*CC*96*4)      // dw [2l][2slot][64][128][96]
#define SZ_SC    ((size_t)3*BB*HH*4)           // f32 c-state
#define SZ_SH    ((size_t)3*BB*96*4)           // dword h-state (f16 pairs)

__device__ __forceinline__ float sigmf(float x) { return 1.0f/(1.0f + __expf(-x)); }
__device__ __forceinline__ float tanhf_(float x) { return 2.0f/(1.0f + __expf(-2.0f*x)) - 1.0f; }

// ---------------------------------------------------------------------------
// weight prep: wih compact [3][656][192] (K zero-padded), whh padded
// [3][704][192] (rows g*176+e, zero for e>=164; K zero-padded)
// ---------------------------------------------------------------------------
__global__ void kprep_w(const float* wih0, const float* whh0,
                        const float* wih1, const float* whh1,
                        const float* wih2, const float* whh2,
                        _Float16* wih16, _Float16* whh16) {
  int i = threadIdx.x + blockIdx.x * blockDim.x;
  if (i >= 3*GP*KPH) return;
  int l = i / (GP*KPH);
  int r2 = i - l*(GP*KPH);
  int prow = r2 / KPH;
  int k = r2 - prow*KPH;
  const float* wihl = (l == 0) ? wih0 : ((l == 1) ? wih1 : wih2);
  const float* whhl = (l == 0) ? whh0 : ((l == 1) ? whh1 : whh2);
  int g = prow / EP, e = prow - g*EP;
  float vh = 0.f;
  if (e < HH && k < HH) vh = whhl[(size_t)(g*HH + e)*HH + k];
  whh16[((size_t)l*GP + prow)*KPH + k] = (_Float16)vh;
  if (prow < GG) {
    float vi = 0.f;
    if (l == 0) { if (k < 40) vi = wihl[(size_t)prow*40 + k]; }
    else        { if (k < HH) vi = wihl[(size_t)prow*HH + k]; }
    wih16[((size_t)l*GG + prow)*KPH + k] = (_Float16)vi;
  }
}

// ---------------------------------------------------------------------------
// batch-major input GEMM: one (l, bg, 8-t slice). 704 thr (11 waves).
// Per t: A=[16b x K] (LDS, row stride 100 dw), B=W_ih; D m=quad*4+r=batch,
// n=n15 -> gx[t][nt*16+n15][quad*4..+3] = one uint2 store. Bias folded in.
// ---------------------------------------------------------------------------
__device__ __forceinline__ void gemm_body(
    int l, int bg, int ts, int ch, const int* lengths, const float* x,
    const uint32_t* wihw, const uint32_t* hring, const float* bp,
    uint16_t* gxs, uint32_t* smem, int tid) {
  int maxlen = 1;
  #pragma unroll
  for (int bi = 0; bi < 16; ++bi) {
    int L = lengths[bg*16 + bi]; if (L < 1) L = 1; if (L > TT) L = TT;
    if (L > maxlen) maxlen = L;
  }
  const int tb = ts*TSL;                        // local t base within chunk
  const int t0 = ch*CC + tb;                    // absolute t base
  if (t0 >= maxlen) return;
  int tcnt = maxlen - t0; if (tcnt > TSL) tcnt = TSL;

  // ---- stage A: [TSL][16 batches][100 dw], full 96 dw (zeros pad K) ----
  if (l == 0) {
    for (int idx = tid; idx < TSL*16*96; idx += 704) {
      int tloc = idx / 1536, r = idx - tloc*1536, b = r / 96, dw = r - b*96;
      uint32_t v = 0;
      if (dw < 20) {
        const float* xs = x + ((size_t)(bg*16 + b)*TT + (t0 + tloc))*40 + dw*2;
        half2v pp; pp[0] = (_Float16)xs[0]; pp[1] = (_Float16)xs[1];
        v = __builtin_bit_cast(uint32_t, pp);
      }
      smem[(tloc*16 + b)*100 + dw] = v;
    }
  } else {
    const uint32_t* hbs = hring + ((size_t)((l-1)*2 + (ch & 1))*BB)*CC*96;
    for (int idx = tid; idx < TSL*16*96; idx += 704) {
      int tloc = idx / 1536, r = idx - tloc*1536, b = r / 96, dw = r - b*96;
      smem[(tloc*16 + b)*100 + dw] =
          hbs[((size_t)(bg*16 + b)*CC + tb + tloc)*96 + dw];
    }
  }
  __syncthreads();

  const int lane = tid & 63, wv = tid >> 6;
  const int quad = lane >> 4, n15 = lane & 15;
  uint16_t* gxo = gxs + ((size_t)(l*4 + bg)*CC + tb)*GG*16;

  // ---- hoisted W_ih fragments + bias (static indices; regs) ----
  half8 wf[4][6];
  float bv[4] = {0.f, 0.f, 0.f, 0.f};
  #pragma unroll
  for (int ni = 0; ni < 4; ++ni) {
    int nt = wv + ni*11;
    if (nt < 41) {
      int wrow = nt*16 + n15;
      const half8* bsrc = (const half8*)(wihw + ((size_t)l*GG + wrow)*KPD);
      #pragma unroll
      for (int kk = 0; kk < 6; ++kk) wf[ni][kk] = bsrc[kk*4 + quad];
      bv[ni] = bp[wrow];
    }
  }

  for (int tloc = 0; tloc < tcnt; ++tloc) {
    const half8* asrc = (const half8*)(smem + tloc*1600); // batch stride 25 h8
    half8 af[6];
    #pragma unroll
    for (int kk = 0; kk < 6; ++kk) af[kk] = asrc[n15*25 + kk*4 + quad];
    #pragma unroll
    for (int ni = 0; ni < 4; ++ni) {
      int nt = wv + ni*11;
      if (nt < 41) {
        int wrow = nt*16 + n15;
        f32x4 a0 = {0.f,0.f,0.f,0.f};
        #pragma unroll
        for (int kk = 0; kk < 6; ++kk)
          a0 = __builtin_amdgcn_mfma_f32_16x16x32_f16(af[kk], wf[ni][kk], a0, 0, 0, 0);
        half2v p0; p0[0] = (_Float16)(a0[0] + bv[ni]); p0[1] = (_Float16)(a0[1] + bv[ni]);
        half2v p1; p1[0] = (_Float16)(a0[2] + bv[ni]); p1[1] = (_Float16)(a0[3] + bv[ni]);
        uint2 pk;
        pk.x = __builtin_bit_cast(uint32_t, p0);
        pk.y = __builtin_bit_cast(uint32_t, p1);
        *(uint2*)(gxo + ((size_t)tloc*GG + wrow)*16 + quad*4) = pk;
      }
    }
  }
}

// ---------------------------------------------------------------------------
// MFMA recurrence body for one (l, batch-group of 16, chunk). 704 thr.
// wave wv owns elements e = 16wv..16wv+15; lane (n15,quad) holds all 4 gates
// of element e = 16wv+n15 for batches quad*4+r in acc[g][r].
// ---------------------------------------------------------------------------
__device__ __forceinline__ void rec_body(
    int l, int bg, int ch, const int* lengths,
    const uint32_t* whhw, const uint16_t* gxs, uint32_t* hring,
    float* state_c, uint32_t* state_h, uint32_t* smem, int tid) {

  int maxlen = 1;
  #pragma unroll
  for (int bi = 0; bi < 16; ++bi) {
    int L = lengths[bg*16 + bi]; if (L < 1) L = 1; if (L > TT) L = TT;
    if (L > maxlen) maxlen = L;
  }
  const int t0 = ch*CC;
  if (t0 >= maxlen) return;                     // group fully frozen
  int t1 = t0 + CC; if (t1 > maxlen) t1 = maxlen;

  const int wv = tid >> 6, ln = tid & 63;
  const int quad = ln >> 4, n15 = ln & 15;
  const int e = wv*16 + n15;                    // 0..175
  const int evalid = (e < HH);

  int lenv[4];
  #pragma unroll
  for (int r = 0; r < 4; ++r) {
    int L = lengths[bg*16 + quad*4 + r]; if (L < 1) L = 1; if (L > TT) L = TT;
    lenv[r] = L;
  }

  // resident W_hh fragments: 4 gates x 6 k-steps, half8 each (96 VGPRs)
  half8 wB[24];
  {
    const half8* wb8 = (const half8*)(whhw + (size_t)l*GP*KPD);
    #pragma unroll
    for (int g = 0; g < 4; ++g) {
      int row = g*EP + e;
      #pragma unroll
      for (int kk = 0; kk < 6; ++kk)
        wB[g*6 + kk] = wb8[(size_t)row*24 + kk*4 + quad];
    }
  }

  float creg[4] = {0.f, 0.f, 0.f, 0.f};
  if (ch > 0 && evalid) {
    #pragma unroll
    for (int r = 0; r < 4; ++r)
      creg[r] = state_c[((size_t)l*BB + bg*16 + quad*4 + r)*HH + e];
  }

  // h double buffer in LDS: [16 batches][100 dwords], halves 164..191 = 0
  uint32_t* hb0 = smem;
  uint32_t* hb1 = smem + 1600;
  for (int i2 = tid; i2 < 1600; i2 += 704) {
    int bb = i2 / 100, dd = i2 - bb*100;
    uint32_t v = 0;
    if (dd < 96 && ch > 0) v = state_h[((size_t)l*BB + bg*16 + bb)*96 + dd];
    hb0[i2] = v; hb1[i2] = v;
  }
  __syncthreads();

  // per-lane h bits for its 4 (batch, e) slots (re-published every step so
  // frozen sequences keep valid h in BOTH buffers)
  uint16_t hbits[4];
  #pragma unroll
  for (int r = 0; r < 4; ++r)
    hbits[r] = ((const uint16_t*)hb0)[(quad*4 + r)*200 + e];

  uint32_t* hrb = (l < 2)
      ? hring + ((size_t)(l*2 + (ch & 1))*BB)*CC*96 : (uint32_t*)0;
  const uint16_t* gxb = gxs + ((size_t)(l*4 + bg)*CC)*GG*16;
  uint32_t* shb = state_h + ((size_t)l*BB + bg*16)*96;

  // ring-publish slots (1536 dwords over 704 threads = 2..3 per thread),
  // indices hoisted out of the step loop (no per-step int division)
  const int rb0 = tid / 96,          rd0 = tid - rb0*96;
  const int i1s = tid + 704;
  const int rb1 = i1s / 96,          rd1 = i1s - rb1*96;
  const int i2s = tid + 1408;
  const int rb2 = i2s / 96,          rd2 = i2s - rb2*96;
  const int has2 = (i2s < 1536);
  const int lsrc0 = rb0*100 + rd0, lsrc1 = rb1*100 + rd1, lsrc2 = rb2*100 + rd2;
  uint32_t* hr0 = hrb ? hrb + ((size_t)(bg*16 + rb0)*CC)*96 + rd0 : (uint32_t*)0;
  uint32_t* hr1 = hrb ? hrb + ((size_t)(bg*16 + rb1)*CC)*96 + rd1 : (uint32_t*)0;
  uint32_t* hr2 = hrb ? hrb + ((size_t)(bg*16 + rb2)*CC)*96 + rd2 : (uint32_t*)0;

  uint2 gxp[4] = {};
  if (evalid) {
    #pragma unroll
    for (int g = 0; g < 4; ++g)
      gxp[g] = *(const uint2*)(gxb + ((size_t)g*HH + e)*16 + quad*4);
  }

  int p = 0;
  for (int t = t0; t < t1; ++t) {
    uint32_t* hin  = p ? hb1 : hb0;
    uint32_t* hout = p ? hb0 : hb1;

    // acc init = gx (bias already folded in by gemm)
    f32x4 acc[4];
    #pragma unroll
    for (int g = 0; g < 4; ++g) {
      const _Float16* gh = (const _Float16*)&gxp[g];
      #pragma unroll
      for (int r = 0; r < 4; ++r) acc[g][r] = (float)gh[r];
    }
    // prefetch next step's gx (hidden under MFMA + update)
    if (t + 1 < t1 && evalid) {
      int trow = t + 1 - t0;
      #pragma unroll
      for (int g = 0; g < 4; ++g)
        gxp[g] = *(const uint2*)(gxb + ((size_t)trow*GG + g*HH + e)*16 + quad*4);
    }
    // recurrent projection: [16x164] @ W_hh^T, 24 MFMA
    #pragma unroll
    for (int kk = 0; kk < 6; ++kk) {
      half8 af = *(const half8*)&hin[n15*100 + kk*16 + quad*4];
      acc[0] = __builtin_amdgcn_mfma_f32_16x16x32_f16(af, wB[kk],      acc[0], 0, 0, 0);
      acc[1] = __builtin_amdgcn_mfma_f32_16x16x32_f16(af, wB[6 + kk],  acc[1], 0, 0, 0);
      acc[2] = __builtin_amdgcn_mfma_f32_16x16x32_f16(af, wB[12 + kk], acc[2], 0, 0, 0);
      acc[3] = __builtin_amdgcn_mfma_f32_16x16x32_f16(af, wB[18 + kk], acc[3], 0, 0, 0);
    }
    // ring publish h(t-1) from hin
    if (hrb && t > t0) {
      int row96 = (t - 1 - t0)*96;
      hr0[row96] = hin[lsrc0];
      hr1[row96] = hin[lsrc1];
      if (has2) hr2[row96] = hin[lsrc2];
    }
    // cell update: lane has gates i,f,g,o of element e for 4 batches
    #pragma unroll
    for (int r = 0; r < 4; ++r) {
      float gi = acc[0][r], gf = acc[1][r], gg2 = acc[2][r], go = acc[3][r];
      float cn = sigmf(gf)*creg[r] + sigmf(gi)*tanhf_(gg2);
      float hv = sigmf(go)*tanhf_(cn);
      if (t < lenv[r]) {                        // per-batch freeze
        creg[r] = cn;
        _Float16 h16 = (_Float16)hv;
        hbits[r] = __builtin_bit_cast(uint16_t, h16);
      }
      if (evalid)
        ((uint16_t*)hout)[(quad*4 + r)*200 + e] = hbits[r];
    }
    // lgkm-only barrier: no vmcnt drain (ring stores / gx prefetch float).
    // All cross-wave data in this loop is LDS (hbuf), covered by lgkmcnt.
    asm volatile("s_waitcnt lgkmcnt(0)" ::: "memory");
    __builtin_amdgcn_s_barrier();
    p ^= 1;
  }

  // final ring publish + persist state
  uint32_t* hfin = p ? hb1 : hb0;
  {
    int rowl96 = (t1 - 1 - t0)*96;
    if (hrb) {
      hr0[rowl96] = hfin[lsrc0];
      hr1[rowl96] = hfin[lsrc1];
      if (has2) hr2[rowl96] = hfin[lsrc2];
    }
    shb[(size_t)rb0*96 + rd0] = hfin[lsrc0];
    shb[(size_t)rb1*96 + rd1] = hfin[lsrc1];
    if (has2) shb[(size_t)rb2*96 + rd2] = hfin[lsrc2];
  }
  if (evalid) {
    #pragma unroll
    for (int r = 0; r < 4; ++r)
      state_c[((size_t)l*BB + bg*16 + quad*4 + r)*HH + e] = creg[r];
  }
}

// ---------------------------------------------------------------------------
// fused step: blocks 0..191 = gemm(l, bg, tslice, ch=j-2l),
//             blocks 192..203 = rec(l, bg, ch=j-2l-1)
// gx double-buffered by chunk parity.
// __launch_bounds__(704, 1): ONE 11-wave block/CU -> 3 waves on fullest
// SIMD -> 170-VGPR cap -> wB register-resident (v5's (704,3) forced an
// 85-reg budget and spilled it).
// ---------------------------------------------------------------------------
__global__ __launch_bounds__(704, 1) void kstep_f(
    int j, const int* lengths, const float* x,
    const uint32_t* wihw, const uint32_t* whhw,
    const float* b0, const float* b1, const float* b2,
    uint16_t* gx, uint32_t* hring, float* state_c, uint32_t* state_h) {
  __shared__ __align__(16) uint32_t smem[TSL*1600];     // 51.2 KB
  const int blk = blockIdx.x, tid = threadIdx.x;
  if (blk < 192) {
    const int l = blk >> 6, r = blk & 63, bg = r >> 4, ts = r & 15;
    const int ch = j - 2*l;
    if (ch < 0 || ch >= NCH) return;
    const float* bp = (l == 0) ? b0 : ((l == 1) ? b1 : b2);
    uint16_t* gxs = gx + (size_t)(ch & 1)*GX_SLOT_HALVES;
    gemm_body(l, bg, ts, ch, lengths, x, wihw, hring, bp, gxs, smem, tid);
  } else {
    const int idx = blk - 192;
    if (idx >= 12) return;
    const int l = idx >> 2, bg = idx & 3;
    const int ch = j - 2*l - 1;
    if (ch < 0 || ch >= NCH) return;
    const uint16_t* gxs = gx + (size_t)(ch & 1)*GX_SLOT_HALVES;
    rec_body(l, bg, ch, lengths, whhw, gxs, hring,
             state_c, state_h, smem, tid);
  }
}

// ---- sequential fallback (1 gx slot; gemm(i) then rec(i) each iteration) ----
__global__ __launch_bounds__(704, 1) void kgemm_s(
    int step, const int* lengths, const float* x,
    const uint32_t* wihw, const float* b0, const float* b1, const float* b2,
    uint16_t* gx, const uint32_t* hring) {
  __shared__ __align__(16) uint32_t smem[TSL*1600];
  const int blk = blockIdx.x;
  const int l = blk >> 6, r = blk & 63, bg = r >> 4, ts = r & 15;
  const int ch = step - l;
  if (ch < 0 || ch >= NCH) return;
  const float* bp = (l == 0) ? b0 : ((l == 1) ? b1 : b2);
  gemm_body(l, bg, ts, ch, lengths, x, wihw, hring, bp, gx, smem, threadIdx.x);
}

__global__ __launch_bounds__(704, 1) void krec_s(
    int step, const int* lengths,
    const uint32_t* whhw, const uint16_t* gx, uint32_t* hring,
    float* state_c, uint32_t* state_h) {
  __shared__ __align__(16) uint32_t smem[TSL*1600];
  const int idx = blockIdx.x;
  const int l = idx >> 2, bg = idx & 3;
  const int ch = step - l;
  if (ch < 0 || ch >= NCH) return;
  rec_body(l, bg, ch, lengths, whhw, gx, hring,
           state_c, state_h, smem, threadIdx.x);
}

// ---------------------------------------------------------------------------
// FC epilogue on layer-2 final hidden state
// ---------------------------------------------------------------------------
__global__ void kfc(const float* fcw, const float* fcb,
                    const uint32_t* state_h, float* out) {
  int b = blockIdx.x, o = threadIdx.x;
  if (o >= 7) return;
  const uint16_t* h16 = (const uint16_t*)(state_h + (size_t)(2*BB + b)*96);
  float s = fcb[o];
  for (int m = 0; m < HH; ++m) {
    _Float16 hv = __builtin_bit_cast(_Float16, h16[m]);
    s += fcw[o*HH + m] * (float)hv;
  }
  out[b*7 + o] = s;
}

// ---------------------------------------------------------------------------
extern "C" void kernel_launch(void* const* d_in, const int* in_sizes, int n_in,
                              void* d_out, int out_size, void* d_ws, size_t ws_size,
                              hipStream_t stream) {
  const float* x      = (const float*)d_in[0];
  const int*  lengths = (const int*)  d_in[1];
  const float* wih0   = (const float*)d_in[2];
  const float* whh0   = (const float*)d_in[3];
  const float* b0     = (const float*)d_in[4];
  const float* wih1   = (const float*)d_in[5];
  const float* whh1   = (const float*)d_in[6];
  const float* b1     = (const float*)d_in[7];
  const float* wih2   = (const float*)d_in[8];
  const float* whh2   = (const float*)d_in[9];
  const float* b2     = (const float*)d_in[10];
  const float* fcw    = (const float*)d_in[11];
  const float* fcb    = (const float*)d_in[12];

  const size_t off_wih = 0;
  const size_t off_whh = SZ_WIH;
  const size_t off_gx  = SZ_WIH + SZ_WHH;
  const size_t tail    = SZ_HR + SZ_SC + SZ_SH;
  const size_t need_fused = off_gx + 2*SZ_GX1 + tail;   // ~78.8 MB
  const size_t need_seq   = off_gx + 1*SZ_GX1 + tail;   // ~46.6 MB
  const int fused = (ws_size >= need_fused);
  if (!fused && ws_size < need_seq) return;             // loud, clean failure
  const size_t gx_bytes = fused ? 2*SZ_GX1 : SZ_GX1;
  const size_t off_hr = off_gx + gx_bytes;
  const size_t off_sc = off_hr + SZ_HR;
  const size_t off_sh = off_sc + SZ_SC;

  char* ws = (char*)d_ws;
  _Float16* wih16 = (_Float16*)(ws + off_wih);
  _Float16* whh16 = (_Float16*)(ws + off_whh);
  uint16_t* gxw   = (uint16_t*)(ws + off_gx);
  uint32_t* hrw   = (uint32_t*)(ws + off_hr);
  float*    scw   = (float*)   (ws + off_sc);
  uint32_t* shw   = (uint32_t*)(ws + off_sh);

  hipLaunchKernelGGL(kprep_w, dim3((3*GP*KPH + 255)/256), dim3(256), 0, stream,
                     wih0, whh0, wih1, whh1, wih2, whh2, wih16, whh16);

  if (fused) {
    for (int jj = 0; jj <= NCH + 4; ++jj) {             // j = 0..20
      hipLaunchKernelGGL(kstep_f, dim3(204), dim3(704), 0, stream,
                         jj, lengths, x, (const uint32_t*)wih16,
                         (const uint32_t*)whh16, b0, b1, b2,
                         gxw, hrw, scw, shw);
    }
  } else {
    for (int i = 0; i < NCH + 2; ++i) {
      hipLaunchKernelGGL(kgemm_s, dim3(192), dim3(704), 0, stream,
                         i, lengths, x, (const uint32_t*)wih16,
                         b0, b1, b2, gxw, (const uint32_t*)hrw);
      hipLaunchKernelGGL(krec_s, dim3(12), dim3(704), 0, stream,
                         i, lengths, (const uint32_t*)whh16,
                         (const uint16_t*)gxw, hrw, scw, shw);
    }
  }

  hipLaunchKernelGGL(kfc, dim3(64), dim3(64), 0, stream,
                     fcw, fcb, shw, (float*)d_out);
}